// Round 1
// baseline (152.244 us; speedup 1.0000x reference)
//
#include <hip/hip_runtime.h>
#include <hip/hip_fp16.h>
#include <stdint.h>

#define BATCH 4096
#define N_IN  512
#define H1    1536
#define H2    1536
#define N_OUT 512
#define FAN   32
#define E0 (H1 * FAN)
#define E1 (H2 * FAN)
#define E2 (N_OUT * FAN)
#define ETOT (E0 + E1 + E2)
#define NNODES (H1 + H2 + N_OUT)   // 3584 non-input nodes
#define MAXDEG 128                 // slot capacity; Poisson(32) max ~54, 128 = guard-free staging

// ---- workspace layout (bytes), total 37,238,784 (< 38.7 MB proven safe) ----
// nv    : 4096 rows x 4096 cols x 2B (fp16) = 33,554,432
//         rows 0..511 = x^T, 512..2047 = h1, 2048..3583 = h2, 3584..4095 = out^T
// edges : slotted [NNODES][MAXDEG] int2 = 3,670,016
// cnt   : NNODES ints = 14,336
#define OFF_EDGES 33554432
#define OFF_CNT   (OFF_EDGES + NNODES * MAXDEG * 8)

// ---------- x [B, N_IN] fp32 -> rows 0..511 of nv (fp16, [node][batch]) ----------
__global__ __launch_bounds__(256) void k_transpose_in(const float* __restrict__ x,
                                                      __half* __restrict__ xT) {
    __shared__ float tile[32][33];
    const int tx = threadIdx.x, ty = threadIdx.y;   // 32 x 8
    const int n0 = blockIdx.x * 32;                 // node base
    const int b0 = blockIdx.y * 32;                 // batch base
#pragma unroll
    for (int k = 0; k < 32; k += 8)
        tile[ty + k][tx] = x[(size_t)(b0 + ty + k) * N_IN + (n0 + tx)];
    __syncthreads();
#pragma unroll
    for (int k = 0; k < 32; k += 8)
        xT[(size_t)(n0 + ty + k) * BATCH + (b0 + tx)] = __float2half_rn(tile[tx][ty + k]);
}

// ---------- slotted edge-table fill: one pass, no scan ----------
__global__ __launch_bounds__(256) void k_fill(const int* __restrict__ s0, const int* __restrict__ d0, const float* __restrict__ w0,
                                              const int* __restrict__ s1, const int* __restrict__ d1, const float* __restrict__ w1,
                                              const int* __restrict__ s2, const int* __restrict__ d2, const float* __restrict__ w2,
                                              int* __restrict__ cnt, int2* __restrict__ edges) {
    const int e = blockIdx.x * 256 + threadIdx.x;
    int src, node; float w;
    if (e < E0)           { src = s0[e];          node = d0[e];                w = w0[e]; }
    else if (e < E0 + E1) { int i = e - E0;       src = s1[i]; node = H1 + d1[i];        w = w1[i]; }
    else                  { int i = e - E0 - E1;  src = s2[i]; node = H1 + H2 + d2[i];   w = w2[i]; }
    const int pos = atomicAdd(&cnt[node], 1);
    if (pos < MAXDEG) edges[node * MAXDEG + pos] = make_int2(src, __float_as_int(w));
}

// ---------- pad each node's slot list to a multiple of 8 with {src=0, w=0} ----------
// Row 0 of nv is real finite data (x^T row 0), so w=0 edges contribute exactly 0.
// This guarantees k_level's inner trip count m is a multiple of 8 (>= 8 when entered),
// enabling a branch-free depth-2 software pipeline.
__global__ __launch_bounds__(256) void k_pad(int* __restrict__ cnt, int2* __restrict__ edges) {
    const int n = blockIdx.x * 256 + threadIdx.x;
    if (n >= NNODES) return;
    int c = cnt[n];
    c = (c < 0) ? 0 : (c > MAXDEG ? MAXDEG : c);
    const int cp = (c + 7) & ~7;          // <= 128 since c <= 128
    for (int p = c; p < cp; ++p)
        edges[(size_t)n * MAXDEG + p] = make_int2(0, 0);
    cnt[n] = cp;
}

// ---------- level kernel: 256 thr = 4 waves, wave = one node, 8 col-tiles ----------
// Linear block id = 8*y + x -> tile x pins to XCD x (%8 round-robin heuristic);
// per-XCD gather footprint = prev_nodes * 512 cols * 2B <= 3.5 MB (fits 4 MB L2).
// Edges staged in VGPRs (lane i holds edge i), read back via readlane — scalar
// gather base. Inner loop is a manual depth-2 software pipeline (groups of 4 edges,
// ping-pong A/B register sets): 8 gathers stay in flight across each consume,
// vmcnt never drains to 0 mid-loop (runtime-trip-count loops don't get
// software-pipelined by LLVM — this is the hand-rotated version).
__global__ __launch_bounds__(256, 4)
void k_level(const int2* __restrict__ edges,   // pre-offset: level base * MAXDEG
             const int* __restrict__ cnt,      // pre-offset: level node base
             const uint4* __restrict__ nv,     // 512 uint4 per node row (fp16 x8)
             uint4* __restrict__ outb) {       // pre-offset row base (uint4 units)
    const int lane = threadIdx.x & 63;
    const int wv   = threadIdx.x >> 6;
    const int node = (blockIdx.y << 2) | wv;
    const int col8 = (blockIdx.x << 6) | lane;  // uint4 index in row, 0..511

    const int c = cnt[node];   // clamped + padded to mult of 8 by k_pad

    float a0 = 0.f, a1 = 0.f, a2 = 0.f, a3 = 0.f, a4 = 0.f, a5 = 0.f, a6 = 0.f, a7 = 0.f;

#define ACC8(q, W) {                                                    \
    const __half2 h0 = *(const __half2*)&(q).x;                         \
    const __half2 h1 = *(const __half2*)&(q).y;                         \
    const __half2 h2 = *(const __half2*)&(q).z;                         \
    const __half2 h3 = *(const __half2*)&(q).w;                         \
    a0 = fmaf(__low2float(h0),  (W), a0);                               \
    a1 = fmaf(__high2float(h0), (W), a1);                               \
    a2 = fmaf(__low2float(h1),  (W), a2);                               \
    a3 = fmaf(__high2float(h1), (W), a3);                               \
    a4 = fmaf(__low2float(h2),  (W), a4);                               \
    a5 = fmaf(__high2float(h2), (W), a5);                               \
    a6 = fmaf(__low2float(h3),  (W), a6);                               \
    a7 = fmaf(__high2float(h3), (W), a7); }

#define RL1(J, S, W) {                                                  \
    S = __builtin_amdgcn_readlane(my.x, (J)) & 4095;                    \
    W = __int_as_float(__builtin_amdgcn_readlane(my.y, (J))); }

#define RLG(J, S0,S1,S2,S3, W0,W1,W2,W3)                                \
    RL1((J),   S0, W0) RL1((J)+1, S1, W1)                               \
    RL1((J)+2, S2, W2) RL1((J)+3, S3, W3)

#define LDG(S0,S1,S2,S3, Q0,Q1,Q2,Q3)                                   \
    Q0 = nv[((size_t)(S0) << 9) | col8];                                \
    Q1 = nv[((size_t)(S1) << 9) | col8];                                \
    Q2 = nv[((size_t)(S2) << 9) | col8];                                \
    Q3 = nv[((size_t)(S3) << 9) | col8];

#define ACCG(Q0,Q1,Q2,Q3, W0,W1,W2,W3)                                  \
    ACC8(Q0, W0) ACC8(Q1, W1) ACC8(Q2, W2) ACC8(Q3, W3)

    for (int base = 0; base < c; base += 64) {
        // stage up to 64 edges of this wave's node into registers (always in-bounds)
        const int2 my = edges[(size_t)node * MAXDEG + base + lane];
        const int m = (c - base < 64) ? (c - base) : 64;   // mult of 8, >= 8

        int sA0, sA1, sA2, sA3, sB0, sB1, sB2, sB3;
        float wA0, wA1, wA2, wA3, wB0, wB1, wB2, wB3;
        uint4 qA0, qA1, qA2, qA3, qB0, qB1, qB2, qB3;

        // prologue: two groups (8 gathers) in flight
        RLG(0, sA0,sA1,sA2,sA3, wA0,wA1,wA2,wA3)
        LDG(sA0,sA1,sA2,sA3, qA0,qA1,qA2,qA3)
        RLG(4, sB0,sB1,sB2,sB3, wB0,wB1,wB2,wB3)
        LDG(sB0,sB1,sB2,sB3, qB0,qB1,qB2,qB3)

        int j = 8;
        for (; j + 8 <= m; j += 8) {
            ACCG(qA0,qA1,qA2,qA3, wA0,wA1,wA2,wA3)
            RLG(j, sA0,sA1,sA2,sA3, wA0,wA1,wA2,wA3)
            LDG(sA0,sA1,sA2,sA3, qA0,qA1,qA2,qA3)
            ACCG(qB0,qB1,qB2,qB3, wB0,wB1,wB2,wB3)
            RLG(j+4, sB0,sB1,sB2,sB3, wB0,wB1,wB2,wB3)
            LDG(sB0,sB1,sB2,sB3, qB0,qB1,qB2,qB3)
        }
        // epilogue: drain the two in-flight groups
        ACCG(qA0,qA1,qA2,qA3, wA0,wA1,wA2,wA3)
        ACCG(qB0,qB1,qB2,qB3, wB0,wB1,wB2,wB3)
    }
#undef ACCG
#undef LDG
#undef RLG
#undef RL1
#undef ACC8

    a0 = fmaxf(a0, 0.f); a1 = fmaxf(a1, 0.f); a2 = fmaxf(a2, 0.f); a3 = fmaxf(a3, 0.f);
    a4 = fmaxf(a4, 0.f); a5 = fmaxf(a5, 0.f); a6 = fmaxf(a6, 0.f); a7 = fmaxf(a7, 0.f);

    const __half2 h0 = __floats2half2_rn(a0, a1);
    const __half2 h1 = __floats2half2_rn(a2, a3);
    const __half2 h2 = __floats2half2_rn(a4, a5);
    const __half2 h3 = __floats2half2_rn(a6, a7);
    uint4 p;
    p.x = *(const uint32_t*)&h0; p.y = *(const uint32_t*)&h1;
    p.z = *(const uint32_t*)&h2; p.w = *(const uint32_t*)&h3;
    outb[((size_t)node << 9) | col8] = p;
}

// ---------- out^T rows (fp16, [N_OUT][B]) -> d_out [B, N_OUT] fp32 ----------
__global__ __launch_bounds__(256) void k_transpose_out(const __half* __restrict__ outh,
                                                       float* __restrict__ out) {
    __shared__ float tile[32][33];
    const int tx = threadIdx.x, ty = threadIdx.y;   // 32 x 8
    const int n0 = blockIdx.x * 32;
    const int b0 = blockIdx.y * 32;
#pragma unroll
    for (int k = 0; k < 32; k += 8)
        tile[ty + k][tx] = __half2float(outh[(size_t)(n0 + ty + k) * BATCH + (b0 + tx)]);
    __syncthreads();
#pragma unroll
    for (int k = 0; k < 32; k += 8)
        out[(size_t)(b0 + ty + k) * N_OUT + (n0 + tx)] = tile[tx][ty + k];
}

extern "C" void kernel_launch(void* const* d_in, const int* in_sizes, int n_in,
                              void* d_out, int out_size, void* d_ws, size_t ws_size,
                              hipStream_t stream) {
    const float* x  = (const float*)d_in[0];
    const int* s0   = (const int*)d_in[1];
    const int* dd0  = (const int*)d_in[2];
    const float* w0 = (const float*)d_in[3];
    const int* s1   = (const int*)d_in[4];
    const int* dd1  = (const int*)d_in[5];
    const float* w1 = (const float*)d_in[6];
    const int* s2   = (const int*)d_in[7];
    const int* dd2  = (const int*)d_in[8];
    const float* w2 = (const float*)d_in[9];

    char* ws        = (char*)d_ws;
    uint4*    nv4   = (uint4*)ws;                    // fp16 node rows, 512 uint4/row
    int2*     edges = (int2*)(ws + OFF_EDGES);
    int*      cnt   = (int*)(ws + OFF_CNT);

    // slotted edge build: memset + one massively-parallel fill (no scan) + pad-to-8
    hipMemsetAsync(cnt, 0, NNODES * sizeof(int), stream);
    k_fill<<<ETOT / 256, 256, 0, stream>>>(s0, dd0, w0, s1, dd1, w1, s2, dd2, w2, cnt, edges);
    k_pad<<<(NNODES + 255) / 256, 256, 0, stream>>>(cnt, edges);

    // x -> fp16 transposed node-value rows 0..511
    k_transpose_in<<<dim3(N_IN / 32, BATCH / 32), dim3(32, 8), 0, stream>>>(x, (__half*)ws);

    // levels: grid (8 col-tiles, H/4), 256 threads = 4 waves = 4 nodes
    k_level<<<dim3(8, H1 / 4), 256, 0, stream>>>(edges, cnt, nv4,
                                                 nv4 + (size_t)N_IN * 512);
    k_level<<<dim3(8, H2 / 4), 256, 0, stream>>>(edges + (size_t)H1 * MAXDEG, cnt + H1, nv4,
                                                 nv4 + (size_t)(N_IN + H1) * 512);
    k_level<<<dim3(8, N_OUT / 4), 256, 0, stream>>>(edges + (size_t)(H1 + H2) * MAXDEG, cnt + H1 + H2, nv4,
                                                    nv4 + (size_t)(N_IN + H1 + H2) * 512);

    // out^T (fp16) -> d_out [B, N_OUT] fp32
    k_transpose_out<<<dim3(N_OUT / 32, BATCH / 32), dim3(32, 8), 0, stream>>>(
        (const __half*)(ws + (size_t)(N_IN + H1 + H2) * BATCH * 2), (float*)d_out);
}

// Round 2
// 147.638 us; speedup vs baseline: 1.0312x; 1.0312x over previous
//
#include <hip/hip_runtime.h>
#include <hip/hip_fp16.h>
#include <stdint.h>

#define BATCH 4096
#define N_IN  512
#define H1    1536
#define H2    1536
#define N_OUT 512
#define FAN   32
#define E0 (H1 * FAN)
#define E1 (H2 * FAN)
#define E2 (N_OUT * FAN)
#define ETOT (E0 + E1 + E2)
#define NNODES (H1 + H2 + N_OUT)   // 3584 non-input nodes
#define MAXDEG 128                 // slot capacity; Poisson(32) max ~54, 128 = guard-free staging

// ---- workspace layout (bytes), total 37,238,784 (< 38.7 MB proven safe) ----
// nv    : 4096 rows x 4096 cols x 2B (fp16) = 33,554,432
//         rows 0..511 = x^T, 512..2047 = h1, 2048..3583 = h2, 3584..4095 = out^T
// edges : slotted [NNODES][MAXDEG] int2 = 3,670,016
// cnt   : NNODES ints = 14,336
#define OFF_EDGES 33554432
#define OFF_CNT   (OFF_EDGES + NNODES * MAXDEG * 8)

// ---------- x [B, N_IN] fp32 -> rows 0..511 of nv (fp16, [node][batch]) ----------
__global__ __launch_bounds__(256) void k_transpose_in(const float* __restrict__ x,
                                                      __half* __restrict__ xT) {
    __shared__ float tile[32][33];
    const int tx = threadIdx.x, ty = threadIdx.y;   // 32 x 8
    const int n0 = blockIdx.x * 32;                 // node base
    const int b0 = blockIdx.y * 32;                 // batch base
#pragma unroll
    for (int k = 0; k < 32; k += 8)
        tile[ty + k][tx] = x[(size_t)(b0 + ty + k) * N_IN + (n0 + tx)];
    __syncthreads();
#pragma unroll
    for (int k = 0; k < 32; k += 8)
        xT[(size_t)(n0 + ty + k) * BATCH + (b0 + tx)] = __float2half_rn(tile[tx][ty + k]);
}

// ---------- slotted edge-table fill: one pass, no scan ----------
__global__ __launch_bounds__(256) void k_fill(const int* __restrict__ s0, const int* __restrict__ d0, const float* __restrict__ w0,
                                              const int* __restrict__ s1, const int* __restrict__ d1, const float* __restrict__ w1,
                                              const int* __restrict__ s2, const int* __restrict__ d2, const float* __restrict__ w2,
                                              int* __restrict__ cnt, int2* __restrict__ edges) {
    const int e = blockIdx.x * 256 + threadIdx.x;
    int src, node; float w;
    if (e < E0)           { src = s0[e];          node = d0[e];                w = w0[e]; }
    else if (e < E0 + E1) { int i = e - E0;       src = s1[i]; node = H1 + d1[i];        w = w1[i]; }
    else                  { int i = e - E0 - E1;  src = s2[i]; node = H1 + H2 + d2[i];   w = w2[i]; }
    const int pos = atomicAdd(&cnt[node], 1);
    if (pos < MAXDEG) edges[node * MAXDEG + pos] = make_int2(src, __float_as_int(w));
}

// ---------- level kernel: 256 thr = 4 waves, wave = one node, 8 col-tiles ----------
// Linear block id = 8*y + x -> tile x pins to XCD x (%8 round-robin heuristic);
// per-XCD gather footprint = prev_nodes * 512 cols * 2B <= 3.5 MB (fits 4 MB L2).
// Edges staged in VGPRs (lane i holds edge i), read back via readlane; weights and
// source indices live in SGPRs, gather base is scalar. Lean register footprint:
// __launch_bounds__(256, 8) caps VGPRs at 64 -> 8 waves/SIMD resident, doubling
// the TLP latency-hiding pool vs the previous ~4-5 waves/SIMD (R1 showed deeper
// per-wave ILP is null; this targets TLP instead).
__global__ __launch_bounds__(256, 8)
void k_level(const int2* __restrict__ edges,   // pre-offset: level base * MAXDEG
             const int* __restrict__ cnt,      // pre-offset: level node base
             const uint4* __restrict__ nv,     // 512 uint4 per node row (fp16 x8)
             uint4* __restrict__ outb) {       // pre-offset row base (uint4 units)
    const int lane = threadIdx.x & 63;
    const int wv   = threadIdx.x >> 6;
    // wave-uniform node id hoisted to SGPR: scalar edge/cnt addressing
    const int node = __builtin_amdgcn_readfirstlane((blockIdx.y << 2) | wv);
    const int col8 = (blockIdx.x << 6) | lane;  // uint4 index in row, 0..511

    int c = cnt[node];
    c = (c < 0) ? 0 : (c > MAXDEG ? MAXDEG : c);

    float a0 = 0.f, a1 = 0.f, a2 = 0.f, a3 = 0.f, a4 = 0.f, a5 = 0.f, a6 = 0.f, a7 = 0.f;

#define ACC8(q, W) {                                                    \
    const __half2 h0 = *(const __half2*)&(q).x;                         \
    const __half2 h1 = *(const __half2*)&(q).y;                         \
    const __half2 h2 = *(const __half2*)&(q).z;                         \
    const __half2 h3 = *(const __half2*)&(q).w;                         \
    a0 = fmaf(__low2float(h0),  (W), a0);                               \
    a1 = fmaf(__high2float(h0), (W), a1);                               \
    a2 = fmaf(__low2float(h1),  (W), a2);                               \
    a3 = fmaf(__high2float(h1), (W), a3);                               \
    a4 = fmaf(__low2float(h2),  (W), a4);                               \
    a5 = fmaf(__high2float(h2), (W), a5);                               \
    a6 = fmaf(__low2float(h3),  (W), a6);                               \
    a7 = fmaf(__high2float(h3), (W), a7); }

    for (int base = 0; base < c; base += 64) {
        // stage up to 64 edges of this wave's node into registers (always in-bounds)
        const int2 my = edges[(size_t)node * MAXDEG + base + lane];
        const int m = (c - base < 64) ? (c - base) : 64;
        int j = 0;
        for (; j + 4 <= m; j += 4) {
            const int   s0i = __builtin_amdgcn_readlane(my.x, j)     & 4095;
            const int   s1i = __builtin_amdgcn_readlane(my.x, j + 1) & 4095;
            const int   s2i = __builtin_amdgcn_readlane(my.x, j + 2) & 4095;
            const int   s3i = __builtin_amdgcn_readlane(my.x, j + 3) & 4095;
            const float wa  = __int_as_float(__builtin_amdgcn_readlane(my.y, j));
            const float wb  = __int_as_float(__builtin_amdgcn_readlane(my.y, j + 1));
            const float wc  = __int_as_float(__builtin_amdgcn_readlane(my.y, j + 2));
            const float wd  = __int_as_float(__builtin_amdgcn_readlane(my.y, j + 3));
            const uint4 q0 = nv[((size_t)s0i << 9) | col8];
            const uint4 q1 = nv[((size_t)s1i << 9) | col8];
            const uint4 q2 = nv[((size_t)s2i << 9) | col8];
            const uint4 q3 = nv[((size_t)s3i << 9) | col8];
            ACC8(q0, wa);
            ACC8(q1, wb);
            ACC8(q2, wc);
            ACC8(q3, wd);
        }
        for (; j < m; ++j) {
            const int   s0i = __builtin_amdgcn_readlane(my.x, j) & 4095;
            const float wa  = __int_as_float(__builtin_amdgcn_readlane(my.y, j));
            const uint4 q0 = nv[((size_t)s0i << 9) | col8];
            ACC8(q0, wa);
        }
    }
#undef ACC8

    a0 = fmaxf(a0, 0.f); a1 = fmaxf(a1, 0.f); a2 = fmaxf(a2, 0.f); a3 = fmaxf(a3, 0.f);
    a4 = fmaxf(a4, 0.f); a5 = fmaxf(a5, 0.f); a6 = fmaxf(a6, 0.f); a7 = fmaxf(a7, 0.f);

    const __half2 h0 = __floats2half2_rn(a0, a1);
    const __half2 h1 = __floats2half2_rn(a2, a3);
    const __half2 h2 = __floats2half2_rn(a4, a5);
    const __half2 h3 = __floats2half2_rn(a6, a7);
    uint4 p;
    p.x = *(const uint32_t*)&h0; p.y = *(const uint32_t*)&h1;
    p.z = *(const uint32_t*)&h2; p.w = *(const uint32_t*)&h3;
    outb[((size_t)node << 9) | col8] = p;
}

// ---------- out^T rows (fp16, [N_OUT][B]) -> d_out [B, N_OUT] fp32 ----------
__global__ __launch_bounds__(256) void k_transpose_out(const __half* __restrict__ outh,
                                                       float* __restrict__ out) {
    __shared__ float tile[32][33];
    const int tx = threadIdx.x, ty = threadIdx.y;   // 32 x 8
    const int n0 = blockIdx.x * 32;
    const int b0 = blockIdx.y * 32;
#pragma unroll
    for (int k = 0; k < 32; k += 8)
        tile[ty + k][tx] = __half2float(outh[(size_t)(n0 + ty + k) * BATCH + (b0 + tx)]);
    __syncthreads();
#pragma unroll
    for (int k = 0; k < 32; k += 8)
        out[(size_t)(b0 + ty + k) * N_OUT + (n0 + tx)] = tile[tx][ty + k];
}

extern "C" void kernel_launch(void* const* d_in, const int* in_sizes, int n_in,
                              void* d_out, int out_size, void* d_ws, size_t ws_size,
                              hipStream_t stream) {
    const float* x  = (const float*)d_in[0];
    const int* s0   = (const int*)d_in[1];
    const int* dd0  = (const int*)d_in[2];
    const float* w0 = (const float*)d_in[3];
    const int* s1   = (const int*)d_in[4];
    const int* dd1  = (const int*)d_in[5];
    const float* w1 = (const float*)d_in[6];
    const int* s2   = (const int*)d_in[7];
    const int* dd2  = (const int*)d_in[8];
    const float* w2 = (const float*)d_in[9];

    char* ws        = (char*)d_ws;
    uint4*    nv4   = (uint4*)ws;                    // fp16 node rows, 512 uint4/row
    int2*     edges = (int2*)(ws + OFF_EDGES);
    int*      cnt   = (int*)(ws + OFF_CNT);

    // slotted edge build: memset + one massively-parallel fill (no scan)
    hipMemsetAsync(cnt, 0, NNODES * sizeof(int), stream);
    k_fill<<<ETOT / 256, 256, 0, stream>>>(s0, dd0, w0, s1, dd1, w1, s2, dd2, w2, cnt, edges);

    // x -> fp16 transposed node-value rows 0..511
    k_transpose_in<<<dim3(N_IN / 32, BATCH / 32), dim3(32, 8), 0, stream>>>(x, (__half*)ws);

    // levels: grid (8 col-tiles, H/4), 256 threads = 4 waves = 4 nodes
    k_level<<<dim3(8, H1 / 4), 256, 0, stream>>>(edges, cnt, nv4,
                                                 nv4 + (size_t)N_IN * 512);
    k_level<<<dim3(8, H2 / 4), 256, 0, stream>>>(edges + (size_t)H1 * MAXDEG, cnt + H1, nv4,
                                                 nv4 + (size_t)(N_IN + H1) * 512);
    k_level<<<dim3(8, N_OUT / 4), 256, 0, stream>>>(edges + (size_t)(H1 + H2) * MAXDEG, cnt + H1 + H2, nv4,
                                                    nv4 + (size_t)(N_IN + H1 + H2) * 512);

    // out^T (fp16) -> d_out [B, N_OUT] fp32
    k_transpose_out<<<dim3(N_OUT / 32, BATCH / 32), dim3(32, 8), 0, stream>>>(
        (const __half*)(ws + (size_t)(N_IN + H1 + H2) * BATCH * 2), (float*)d_out);
}